// Round 2
// baseline (136.363 us; speedup 1.0000x reference)
//
#include <hip/hip_runtime.h>
#include <hip/hip_bf16.h>

#define S_DIM 2048
#define B_DIM 32
#define E_DIM 1024
#define H_DIM 1024

// v_enc/v_dec two-stage reduce
#define VCHUNKS 32           // 32 chunks of 32 h-rows each

// k3 decomposition: each wave handles CH s-rows, 4 waves/block reduce in LDS
#define CH 16
#define WPB 4
#define ROWS_PER_BLOCK (CH * WPB)             // 64
#define BLOCKS_PER_B (S_DIM / ROWS_PER_BLOCK) // 32
#define NBLK (B_DIM * BLOCKS_PER_B)           // 1024

// ---------------- workspace layout (floats) ----------------
// penc  [VCHUNKS][E]      32768
// pdec  [VCHUNKS][H]      32768
// venc  [E]               1024
// vdec  [H]               1024
// expw  [B][S]            65536
// pl    [NBLK]            1024
// pctx  [NBLK][E]         1048576
// total ~4.7 MB

__global__ __launch_bounds__(256) void k1_partial_v(
    const float* __restrict__ W_enc, const float* __restrict__ W_dec,
    const float* __restrict__ w_score, float* __restrict__ penc,
    float* __restrict__ pdec) {
  int bid = blockIdx.x;           // 0..255 (128 enc, 128 dec)
  int t = threadIdx.x;
  bool enc = bid < 128;
  int idx = enc ? bid : bid - 128;
  int hc = idx >> 2;              // 0..31 h-chunk
  int e0 = (idx & 3) << 8;        // 0,256,512,768
  const float* M = enc ? W_enc : W_dec;
  int h0 = hc * 32;
  float acc = 0.f;
#pragma unroll 8
  for (int r = 0; r < 32; ++r) {
    float w = w_score[h0 + r];
    acc = fmaf(w, M[(size_t)(h0 + r) * E_DIM + e0 + t], acc);
  }
  float* dst = enc ? penc : pdec;
  dst[hc * E_DIM + e0 + t] = acc;
}

__global__ __launch_bounds__(256) void k2_finalize_v(
    const float* __restrict__ penc, const float* __restrict__ pdec,
    float* __restrict__ venc, float* __restrict__ vdec) {
  int g = blockIdx.x * 256 + threadIdx.x;  // 0..2047
  bool enc = g < E_DIM;
  const float* p = enc ? penc : pdec;
  int e = enc ? g : g - E_DIM;
  float acc = 0.f;
#pragma unroll 8
  for (int c = 0; c < VCHUNKS; ++c) acc += p[c * E_DIM + e];
  (enc ? venc : vdec)[e] = acc;
}

__device__ __forceinline__ float wave_allreduce_sum(float v) {
#pragma unroll
  for (int off = 1; off < 64; off <<= 1) v += __shfl_xor(v, off, 64);
  return v;
}

__device__ __forceinline__ float fast_tanh(float x) {
  // tanh(x) = 1 - 2/(e^{2x}+1); exact saturation as e^{2x} -> 0 or inf
  float e2 = __expf(2.f * x);
  return 1.f - 2.f * __builtin_amdgcn_rcpf(e2 + 1.f);
}

// Main streaming pass: scores + exp + fused partial weighted-context.
// Grid: NBLK blocks x 256 threads (4 waves). Wave w owns 16 s-rows,
// processed 2 at a time for ILP; block reduces its 4 ctx partials in LDS.
__global__ __launch_bounds__(256, 4) void k3_stream(
    const float* __restrict__ h_enc, const float* __restrict__ h_t,
    const float* __restrict__ venc, const float* __restrict__ vdec,
    float* __restrict__ expw, float* __restrict__ pl,
    float* __restrict__ pctx) {
  int bid = blockIdx.x;
  int t = threadIdx.x;
  int w = t >> 6;
  int lane = t & 63;
  int b = bid >> 5;                 // 32 blocks per b
  int cbi = bid & 31;
  int s0 = cbi * ROWS_PER_BLOCK + w * CH;
  int e_base = lane * 4;            // lane covers e = lane*4 + k*256, k=0..3

  __shared__ float lctx[WPB][E_DIM];   // 16 KB
  __shared__ float ll[WPB];

  float4 ve[4];
#pragma unroll
  for (int k = 0; k < 4; ++k)
    ve[k] = *reinterpret_cast<const float4*>(venc + e_base + k * 256);

  // c_b = vdec . h_t[b]
  float cb = 0.f;
#pragma unroll
  for (int k = 0; k < 4; ++k) {
    float4 vd = *reinterpret_cast<const float4*>(vdec + e_base + k * 256);
    float4 ht = *reinterpret_cast<const float4*>(h_t + b * H_DIM + e_base + k * 256);
    cb = fmaf(vd.x, ht.x, cb);
    cb = fmaf(vd.y, ht.y, cb);
    cb = fmaf(vd.z, ht.z, cb);
    cb = fmaf(vd.w, ht.w, cb);
  }
  cb = wave_allreduce_sum(cb);

  float4 ctx[4];
#pragma unroll
  for (int k = 0; k < 4; ++k) ctx[k] = make_float4(0.f, 0.f, 0.f, 0.f);
  float lsum = 0.f;

  for (int s = s0; s < s0 + CH; s += 2) {
    const float* r0 = h_enc + ((size_t)s * B_DIM + b) * E_DIM + e_base;
    const float* r1 = r0 + (size_t)B_DIM * E_DIM;
    float4 a[4], c[4];
#pragma unroll
    for (int k = 0; k < 4; ++k) {
      a[k] = *reinterpret_cast<const float4*>(r0 + k * 256);
      c[k] = *reinterpret_cast<const float4*>(r1 + k * 256);
    }

    float d0 = 0.f, d1 = 0.f;
#pragma unroll
    for (int k = 0; k < 4; ++k) {
      d0 = fmaf(a[k].x, ve[k].x, d0); d1 = fmaf(c[k].x, ve[k].x, d1);
      d0 = fmaf(a[k].y, ve[k].y, d0); d1 = fmaf(c[k].y, ve[k].y, d1);
      d0 = fmaf(a[k].z, ve[k].z, d0); d1 = fmaf(c[k].z, ve[k].z, d1);
      d0 = fmaf(a[k].w, ve[k].w, d0); d1 = fmaf(c[k].w, ve[k].w, d1);
    }
#pragma unroll
    for (int off = 1; off < 64; off <<= 1) {
      d0 += __shfl_xor(d0, off, 64);
      d1 += __shfl_xor(d1, off, 64);
    }

    float w0 = __expf(fast_tanh(d0 + cb));
    float w1 = __expf(fast_tanh(d1 + cb));
    if (lane == 0)
      *reinterpret_cast<float2*>(expw + b * S_DIM + s) = make_float2(w0, w1);
    lsum += w0 + w1;

#pragma unroll
    for (int k = 0; k < 4; ++k) {
      ctx[k].x = fmaf(w0, a[k].x, fmaf(w1, c[k].x, ctx[k].x));
      ctx[k].y = fmaf(w0, a[k].y, fmaf(w1, c[k].y, ctx[k].y));
      ctx[k].z = fmaf(w0, a[k].z, fmaf(w1, c[k].z, ctx[k].z));
      ctx[k].w = fmaf(w0, a[k].w, fmaf(w1, c[k].w, ctx[k].w));
    }
  }

  // block-level reduction of the 4 waves' partials
#pragma unroll
  for (int k = 0; k < 4; ++k)
    *reinterpret_cast<float4*>(&lctx[w][e_base + k * 256]) = ctx[k];
  if (lane == 0) ll[w] = lsum;
  __syncthreads();

  {
    int e = t * 4;  // each thread reduces 4 consecutive e over the 4 waves
    float4 v0 = *reinterpret_cast<const float4*>(&lctx[0][e]);
    float4 v1 = *reinterpret_cast<const float4*>(&lctx[1][e]);
    float4 v2 = *reinterpret_cast<const float4*>(&lctx[2][e]);
    float4 v3 = *reinterpret_cast<const float4*>(&lctx[3][e]);
    float4 r;
    r.x = (v0.x + v1.x) + (v2.x + v3.x);
    r.y = (v0.y + v1.y) + (v2.y + v3.y);
    r.z = (v0.z + v1.z) + (v2.z + v3.z);
    r.w = (v0.w + v1.w) + (v2.w + v3.w);
    *reinterpret_cast<float4*>(pctx + (size_t)bid * E_DIM + e) = r;
    if (t == 0) pl[bid] = (ll[0] + ll[1]) + (ll[2] + ll[3]);
  }
}

// Final reduce: context = sum(pctx)/l_b ; alphas = expw/l_b
__global__ __launch_bounds__(256) void k4_finalize(
    const float* __restrict__ pl, const float* __restrict__ pctx,
    const float* __restrict__ expw, float* __restrict__ out) {
  int bid = blockIdx.x;  // 0..511 : [0,256) ctx, [256,512) alphas
  int t = threadIdx.x;
  int lane = t & 63;
  bool isCtx = bid < 256;
  int idx = isCtx ? bid : bid - 256;
  int b = idx >> 3;

  __shared__ float s_l;
  __shared__ float s_half[128];

  if (t < 64) {
    float v = (lane < BLOCKS_PER_B) ? pl[b * BLOCKS_PER_B + lane] : 0.f;
    v = wave_allreduce_sum(v);
    if (lane == 0) s_l = v;
  }
  __syncthreads();
  float lb = s_l;

  if (isCtx) {
    int e0 = (idx & 7) * 128;
    int eo = t & 127;
    int c0 = (t >> 7) * 16;  // two halves of the 32 chunks
    const float* base = pctx + (size_t)(b * BLOCKS_PER_B + c0) * E_DIM + e0 + eo;
    float acc = 0.f;
#pragma unroll 8
    for (int c = 0; c < 16; ++c) acc += base[(size_t)c * E_DIM];
    if (t >= 128) s_half[eo] = acc;
    __syncthreads();
    if (t < 128) out[b * E_DIM + e0 + eo] = (acc + s_half[eo]) / lb;
  } else {
    int sb = (idx & 7) * 256;
    int o = b * S_DIM + sb + t;
    out[B_DIM * E_DIM + o] = expw[o] / lb;
  }
}

extern "C" void kernel_launch(void* const* d_in, const int* in_sizes, int n_in,
                              void* d_out, int out_size, void* d_ws, size_t ws_size,
                              hipStream_t stream) {
  const float* h_t     = (const float*)d_in[0];
  const float* h_enc   = (const float*)d_in[1];
  const float* W_enc   = (const float*)d_in[2];
  const float* W_dec   = (const float*)d_in[3];
  const float* w_score = (const float*)d_in[4];
  float* out = (float*)d_out;
  float* ws = (float*)d_ws;

  float* penc = ws;                  // 32768
  float* pdec = penc + 32768;        // 32768
  float* venc = pdec + 32768;        // 1024
  float* vdec = venc + 1024;         // 1024
  float* expw = vdec + 1024;         // 65536
  float* pl   = expw + 65536;        // 1024
  float* pctx = pl + 1024;           // 1048576

  hipLaunchKernelGGL(k1_partial_v, dim3(256), dim3(256), 0, stream,
                     W_enc, W_dec, w_score, penc, pdec);
  hipLaunchKernelGGL(k2_finalize_v, dim3(8), dim3(256), 0, stream,
                     penc, pdec, venc, vdec);
  hipLaunchKernelGGL(k3_stream, dim3(NBLK), dim3(256), 0, stream,
                     h_enc, h_t, venc, vdec, expw, pl, pctx);
  hipLaunchKernelGGL(k4_finalize, dim3(512), dim3(256), 0, stream,
                     pl, pctx, expw, out);
}

// Round 3
// 55.962 us; speedup vs baseline: 2.4367x; 2.4367x over previous
//
#include <hip/hip_runtime.h>
#include <hip/hip_bf16.h>

#define S_DIM 2048
#define B_DIM 32
#define E_DIM 1024
#define H_DIM 1024

// v_enc/v_dec two-stage reduce
#define VCHUNKS 32           // 32 chunks of 32 h-rows each

// k3 decomposition: each wave handles CH s-rows, 4 waves/block reduce in LDS
#define CH 16
#define WPB 4
#define ROWS_PER_BLOCK (CH * WPB)             // 64
#define BLOCKS_PER_B (S_DIM / ROWS_PER_BLOCK) // 32
#define NBLK (B_DIM * BLOCKS_PER_B)           // 1024 blocks = 4/CU

// ---------------- workspace layout (floats) ----------------
// penc  [VCHUNKS][E]      32768
// pdec  [VCHUNKS][H]      32768
// venc  [E]               1024
// vdec  [H]               1024
// expw  [B][S]            65536
// pl    [NBLK]            1024
// pctx  [NBLK][E]         1048576
// total ~4.7 MB

__global__ __launch_bounds__(256) void k1_partial_v(
    const float* __restrict__ W_enc, const float* __restrict__ W_dec,
    const float* __restrict__ w_score, float* __restrict__ penc,
    float* __restrict__ pdec) {
  int bid = blockIdx.x;           // 0..255 (128 enc, 128 dec)
  int t = threadIdx.x;
  bool enc = bid < 128;
  int idx = enc ? bid : bid - 128;
  int hc = idx >> 2;              // 0..31 h-chunk
  int e0 = (idx & 3) << 8;        // 0,256,512,768
  const float* M = enc ? W_enc : W_dec;
  int h0 = hc * 32;
  float acc = 0.f;
#pragma unroll 8
  for (int r = 0; r < 32; ++r) {
    float w = w_score[h0 + r];
    acc = fmaf(w, M[(size_t)(h0 + r) * E_DIM + e0 + t], acc);
  }
  float* dst = enc ? penc : pdec;
  dst[hc * E_DIM + e0 + t] = acc;
}

__global__ __launch_bounds__(256) void k2_finalize_v(
    const float* __restrict__ penc, const float* __restrict__ pdec,
    float* __restrict__ venc, float* __restrict__ vdec) {
  int g = blockIdx.x * 256 + threadIdx.x;  // 0..2047
  bool enc = g < E_DIM;
  const float* p = enc ? penc : pdec;
  int e = enc ? g : g - E_DIM;
  float acc = 0.f;
#pragma unroll 8
  for (int c = 0; c < VCHUNKS; ++c) acc += p[c * E_DIM + e];
  (enc ? venc : vdec)[e] = acc;
}

__device__ __forceinline__ float wave_allreduce_sum(float v) {
#pragma unroll
  for (int off = 1; off < 64; off <<= 1) v += __shfl_xor(v, off, 64);
  return v;
}

__device__ __forceinline__ float fast_tanh(float x) {
  // tanh(x) = 1 - 2/(e^{2x}+1); exact saturation as e^{2x} -> 0 or inf
  float e2 = __expf(2.f * x);
  return 1.f - 2.f * __builtin_amdgcn_rcpf(e2 + 1.f);
}

// Main streaming pass: scores + exp + fused partial weighted-context.
// Grid: NBLK blocks x 256 threads (4 waves). Wave w owns 16 s-rows,
// ONE row per iteration (keeps live-register demand ~60 -> 64-VGPR tier,
// no scratch spill; the R2 2-row version spilled ~190MB). Block reduces
// its 4 ctx partials in LDS.
__global__ __launch_bounds__(256) void k3_stream(
    const float* __restrict__ h_enc, const float* __restrict__ h_t,
    const float* __restrict__ venc, const float* __restrict__ vdec,
    float* __restrict__ expw, float* __restrict__ pl,
    float* __restrict__ pctx) {
  int bid = blockIdx.x;
  int t = threadIdx.x;
  int w = t >> 6;
  int lane = t & 63;
  int b = bid >> 5;                 // 32 blocks per b
  int cbi = bid & 31;
  int s0 = cbi * ROWS_PER_BLOCK + w * CH;
  int e_base = lane * 4;            // lane covers e = lane*4 + k*256, k=0..3

  __shared__ float lctx[WPB][E_DIM];   // 16 KB
  __shared__ float ll[WPB];

  float4 ve[4];
#pragma unroll
  for (int k = 0; k < 4; ++k)
    ve[k] = *reinterpret_cast<const float4*>(venc + e_base + k * 256);

  // c_b = vdec . h_t[b]
  float cb = 0.f;
#pragma unroll
  for (int k = 0; k < 4; ++k) {
    float4 vd = *reinterpret_cast<const float4*>(vdec + e_base + k * 256);
    float4 ht = *reinterpret_cast<const float4*>(h_t + b * H_DIM + e_base + k * 256);
    cb = fmaf(vd.x, ht.x, cb);
    cb = fmaf(vd.y, ht.y, cb);
    cb = fmaf(vd.z, ht.z, cb);
    cb = fmaf(vd.w, ht.w, cb);
  }
  cb = wave_allreduce_sum(cb);

  float4 ctx[4];
#pragma unroll
  for (int k = 0; k < 4; ++k) ctx[k] = make_float4(0.f, 0.f, 0.f, 0.f);
  float lsum = 0.f;

  for (int s = s0; s < s0 + CH; ++s) {
    const float* row = h_enc + ((size_t)s * B_DIM + b) * E_DIM + e_base;
    float4 a[4];
#pragma unroll
    for (int k = 0; k < 4; ++k)
      a[k] = *reinterpret_cast<const float4*>(row + k * 256);

    float d = 0.f;
#pragma unroll
    for (int k = 0; k < 4; ++k) {
      d = fmaf(a[k].x, ve[k].x, d);
      d = fmaf(a[k].y, ve[k].y, d);
      d = fmaf(a[k].z, ve[k].z, d);
      d = fmaf(a[k].w, ve[k].w, d);
    }
    d = wave_allreduce_sum(d);

    float wgt = __expf(fast_tanh(d + cb));
    if (lane == 0) expw[b * S_DIM + s] = wgt;
    lsum += wgt;

#pragma unroll
    for (int k = 0; k < 4; ++k) {
      ctx[k].x = fmaf(wgt, a[k].x, ctx[k].x);
      ctx[k].y = fmaf(wgt, a[k].y, ctx[k].y);
      ctx[k].z = fmaf(wgt, a[k].z, ctx[k].z);
      ctx[k].w = fmaf(wgt, a[k].w, ctx[k].w);
    }
  }

  // block-level reduction of the 4 waves' partials
#pragma unroll
  for (int k = 0; k < 4; ++k)
    *reinterpret_cast<float4*>(&lctx[w][e_base + k * 256]) = ctx[k];
  if (lane == 0) ll[w] = lsum;
  __syncthreads();

  {
    int e = t * 4;  // each thread reduces 4 consecutive e over the 4 waves
    float4 v0 = *reinterpret_cast<const float4*>(&lctx[0][e]);
    float4 v1 = *reinterpret_cast<const float4*>(&lctx[1][e]);
    float4 v2 = *reinterpret_cast<const float4*>(&lctx[2][e]);
    float4 v3 = *reinterpret_cast<const float4*>(&lctx[3][e]);
    float4 r;
    r.x = (v0.x + v1.x) + (v2.x + v3.x);
    r.y = (v0.y + v1.y) + (v2.y + v3.y);
    r.z = (v0.z + v1.z) + (v2.z + v3.z);
    r.w = (v0.w + v1.w) + (v2.w + v3.w);
    *reinterpret_cast<float4*>(pctx + (size_t)bid * E_DIM + e) = r;
    if (t == 0) pl[bid] = (ll[0] + ll[1]) + (ll[2] + ll[3]);
  }
}

// Final reduce: context = sum(pctx)/l_b ; alphas = expw/l_b
__global__ __launch_bounds__(256) void k4_finalize(
    const float* __restrict__ pl, const float* __restrict__ pctx,
    const float* __restrict__ expw, float* __restrict__ out) {
  int bid = blockIdx.x;  // 0..511 : [0,256) ctx, [256,512) alphas
  int t = threadIdx.x;
  int lane = t & 63;
  bool isCtx = bid < 256;
  int idx = isCtx ? bid : bid - 256;
  int b = idx >> 3;

  __shared__ float s_l;
  __shared__ float s_half[128];

  if (t < 64) {
    float v = (lane < BLOCKS_PER_B) ? pl[b * BLOCKS_PER_B + lane] : 0.f;
    v = wave_allreduce_sum(v);
    if (lane == 0) s_l = v;
  }
  __syncthreads();
  float lb = s_l;

  if (isCtx) {
    int e0 = (idx & 7) * 128;
    int eo = t & 127;
    int c0 = (t >> 7) * 16;  // two halves of the 32 chunks
    const float* base = pctx + (size_t)(b * BLOCKS_PER_B + c0) * E_DIM + e0 + eo;
    float acc = 0.f;
#pragma unroll 8
    for (int c = 0; c < 16; ++c) acc += base[(size_t)c * E_DIM];
    if (t >= 128) s_half[eo] = acc;
    __syncthreads();
    if (t < 128) out[b * E_DIM + e0 + eo] = (acc + s_half[eo]) / lb;
  } else {
    int sb = (idx & 7) * 256;
    int o = b * S_DIM + sb + t;
    out[B_DIM * E_DIM + o] = expw[o] / lb;
  }
}

extern "C" void kernel_launch(void* const* d_in, const int* in_sizes, int n_in,
                              void* d_out, int out_size, void* d_ws, size_t ws_size,
                              hipStream_t stream) {
  const float* h_t     = (const float*)d_in[0];
  const float* h_enc   = (const float*)d_in[1];
  const float* W_enc   = (const float*)d_in[2];
  const float* W_dec   = (const float*)d_in[3];
  const float* w_score = (const float*)d_in[4];
  float* out = (float*)d_out;
  float* ws = (float*)d_ws;

  float* penc = ws;                  // 32768
  float* pdec = penc + 32768;        // 32768
  float* venc = pdec + 32768;        // 1024
  float* vdec = venc + 1024;         // 1024
  float* expw = vdec + 1024;         // 65536
  float* pl   = expw + 65536;        // 1024
  float* pctx = pl + 1024;           // 1048576

  hipLaunchKernelGGL(k1_partial_v, dim3(256), dim3(256), 0, stream,
                     W_enc, W_dec, w_score, penc, pdec);
  hipLaunchKernelGGL(k2_finalize_v, dim3(8), dim3(256), 0, stream,
                     penc, pdec, venc, vdec);
  hipLaunchKernelGGL(k3_stream, dim3(NBLK), dim3(256), 0, stream,
                     h_enc, h_t, venc, vdec, expw, pl, pctx);
  hipLaunchKernelGGL(k4_finalize, dim3(512), dim3(256), 0, stream,
                     pl, pctx, expw, out);
}